// Round 6
// baseline (35.314 us; speedup 1.0000x reference)
//
#include <hip/hip_runtime.h>

#define NUM_PAGES 1048576
#define TPP 32
#define SLOTS 256
#define MPPS 4096
#define NBLK 512
#define NTHR 256
// Each block copies int4 range [b*512, b*512+512) of ps and pm,
// i.e. pages [b*2048, (b+1)*2048) == scan chunks {2b, 2b+1} (1024 pages/chunk).

__global__ __launch_bounds__(NTHR) void fused(
    const int* __restrict__ ps, const int* __restrict__ pm,
    const int* __restrict__ seq, const int* __restrict__ npu,
    const int* __restrict__ cp, int* __restrict__ out)
{
    const int t = threadIdx.x, b = blockIdx.x;
    const int lane = t & 63, wave = t >> 6;
    const unsigned long long mlt = (1ULL << lane) - 1ULL;

    int* out_ps  = out;                     // NUM_PAGES
    int* out_pm  = out + NUM_PAGES;         // SLOTS*MPPS == NUM_PAGES
    int* out_seq = out + 2 * NUM_PAGES;
    int* out_npu = out_seq + SLOTS;
    int* out_cp  = out_npu + SLOTS;
    int* out_cpp = out_cp + SLOTS;

    __shared__ int s_w[4];
    __shared__ int s_free[SLOTS];
    __shared__ int s_nfp[SLOTS];            // -1 = slot needs no page
    __shared__ int s_col[SLOTS];            // pm column (npu) per slot
    __shared__ int s_found;

    const int4* ps4 = reinterpret_cast<const int4*>(ps);

    // ---- issue ALL loads up front ------------------------------------------
    const int gi0 = b * (2 * NTHR) + t;     // my two int4 copy elements
    const int gi1 = gi0 + NTHR;
    int4 pv0 = ps4[gi0];
    int4 pv1 = ps4[gi1];
    int4 mv0 = reinterpret_cast<const int4*>(pm)[gi0];
    int4 mv1 = reinterpret_cast<const int4*>(pm)[gi1];
    const int4 pc0 = ps4[t];                // scan prefetch: pages 0..1023
    const int4 pc1 = ps4[NTHR + t];         // pages 1024..2047
    const int4 pc2 = ps4[2 * NTHR + t];     // pages 2048..3071
    const int sq = seq[t], c = cp[t], u = npu[t];

    // ---- phase 1: slot math (t == slot id), every block --------------------
    int ns = sq + (c != -1);
    int nn = (ns + TPP - 1) / TPP;
    int needs = (nn > u) ? 1 : 0;
    unsigned long long bal = __ballot(needs);
    if (lane == 0) s_w[wave] = __popcll(bal);
    if (t == 0) s_found = 0;
    if (b == 0) {                           // no patches ever hit these three
        out_seq[t] = ns;
        out_npu[t] = nn;
        out_cpp[t] = (ns == 0) ? 0 : ((ns - 1) & (TPP - 1));
    }
    __syncthreads();
    int woff = 0;
    for (int w = 0; w < wave; ++w) woff += s_w[w];
    const int r = woff + __popcll(bal & mlt);          // my slot's alloc rank
    const int K = s_w[0] + s_w[1] + s_w[2] + s_w[3];   // slots needing a page
    __syncthreads();                                   // s_w reused below

    // ---- phase 2: find first K free pages; mark own-register patches -------
    int pmask0 = 0, pmask1 = 0;             // bits j: set pv{0,1}[j] = 1
    auto process = [&](int4 v, int ch) {
        int m = ((v.x == 0) ? 1 : 0) | ((v.y == 0) ? 2 : 0) |
                ((v.z == 0) ? 4 : 0) | ((v.w == 0) ? 8 : 0);
        if (ch == 0 && t == 0) m &= ~1;     // page 0 never allocatable
        int q = __popc(m);
        int x = q;                          // inclusive wave scan
        for (int o = 1; o < 64; o <<= 1) { int y = __shfl_up(x, o); if (lane >= o) x += y; }
        if (lane == 63) s_w[wave] = x;
        int sf = s_found;                   // stable since last barrier
        __syncthreads();
        int wo = 0;
        for (int w = 0; w < wave; ++w) wo += s_w[w];
        int pos = sf + wo + x - q;          // excl. global rank of my 1st free
        #pragma unroll
        for (int j = 0; j < 4; ++j) if (m & (1 << j)) {
            int p = pos + __popc(m & ((1 << j) - 1));
            if (p < K) {
                s_free[p] = ch * 1024 + t * 4 + j;
                if (ch == 2 * b)     pmask0 |= 1 << j;   // page lives in my pv0
                if (ch == 2 * b + 1) pmask1 |= 1 << j;   // page lives in my pv1
            }
        }
        if (t == 0) s_found = sf + s_w[0] + s_w[1] + s_w[2] + s_w[3];
        __syncthreads();
    };

    process(pc0, 0);
    if (s_found < K) process(pc1, 1);
    if (s_found < K) process(pc2, 2);
    for (int ch = 3; ch < NUM_PAGES / 1024 && s_found < K; ++ch)
        process(ps4[ch * NTHR + t], ch);    // cold-path correctness fallback

    const int fe = (s_found < K) ? s_found : K;        // frees actually found

    // ---- phase 3: publish per-slot patch info, then patch own registers ----
    const int nfp = (needs && r < fe) ? s_free[r] : 0; // 0 = pool exhausted
    s_nfp[t] = needs ? nfp : -1;
    s_col[t] = u;
    if (b == 0) out_cp[t] = needs ? nfp : c;
    if (fe < K && b == 0 && t == 0) pmask0 |= 1;       // ref sets ps[0]=1 then
    __syncthreads();

    // pm patch: does my int4 cover (slot, col)? (int4 gi covers slot gi>>10,
    // cols (gi&1023)*4 .. +4)
    {
        int s0 = gi0 >> 10, p0 = s_nfp[s0];
        if (p0 != -1) {
            int d = s_col[s0] - ((gi0 & 1023) << 2);
            if ((unsigned)d < 4u) reinterpret_cast<int*>(&mv0)[d] = p0;
        }
        int s1 = gi1 >> 10, p1 = s_nfp[s1];
        if (p1 != -1) {
            int d = s_col[s1] - ((gi1 & 1023) << 2);
            if ((unsigned)d < 4u) reinterpret_cast<int*>(&mv1)[d] = p1;
        }
    }
    // ps patch: set my own free-page elements to 1
    if (pmask0 & 1) pv0.x = 1;
    if (pmask0 & 2) pv0.y = 1;
    if (pmask0 & 4) pv0.z = 1;
    if (pmask0 & 8) pv0.w = 1;
    if (pmask1 & 1) pv1.x = 1;
    if (pmask1 & 2) pv1.y = 1;
    if (pmask1 & 4) pv1.z = 1;
    if (pmask1 & 8) pv1.w = 1;

    // ---- phase 4: single fused copy+patch store, no trailing barrier -------
    reinterpret_cast<int4*>(out_ps)[gi0] = pv0;
    reinterpret_cast<int4*>(out_ps)[gi1] = pv1;
    reinterpret_cast<int4*>(out_pm)[gi0] = mv0;
    reinterpret_cast<int4*>(out_pm)[gi1] = mv1;
}

// ---------------------------------------------------------------------------
extern "C" void kernel_launch(void* const* d_in, const int* in_sizes, int n_in,
                              void* d_out, int out_size, void* d_ws, size_t ws_size,
                              hipStream_t stream)
{
    const int* page_status = (const int*)d_in[0];
    const int* page_map    = (const int*)d_in[1];
    const int* seq         = (const int*)d_in[2];
    const int* npu         = (const int*)d_in[3];
    const int* cp          = (const int*)d_in[4];
    // d_in[5] (current_page_position) unused by the reference update.

    fused<<<NBLK, NTHR, 0, stream>>>(
        page_status, page_map, seq, npu, cp, (int*)d_out);
}

// Round 7
// 11.079 us; speedup vs baseline: 3.1876x; 3.1876x over previous
//
#include <hip/hip_runtime.h>

#define NUM_PAGES 1048576
#define TPP 32
#define SLOTS 256
#define MPPS 4096
#define NBLK 1024
#define NTHR 256
// block b copies int4 gi = b*256+t of ps and pm (1024 ints of each per block)

#define ELEM(v, j) ((j) == 0 ? (v).x : (j) == 1 ? (v).y : (j) == 2 ? (v).z : (v).w)

__global__ __launch_bounds__(NTHR) void fused(
    const int* __restrict__ ps, const int* __restrict__ pm,
    const int* __restrict__ seq, const int* __restrict__ npu,
    const int* __restrict__ cp, int* __restrict__ out)
{
    const int t = threadIdx.x, b = blockIdx.x;
    const int lane = t & 63, wave = t >> 6;

    int* out_ps  = out;                     // NUM_PAGES
    int* out_pm  = out + NUM_PAGES;         // SLOTS*MPPS == NUM_PAGES
    int* out_seq = out + 2 * NUM_PAGES;
    int* out_npu = out_seq + SLOTS;
    int* out_cp  = out_npu + SLOTS;
    int* out_cpp = out_cp + SLOTS;

    __shared__ int s_free[SLOTS];   // ascending free-page ids (first K)
    __shared__ int s_info[SLOTS];   // per-slot alloc rank, or -1
    __shared__ int s_col[SLOTS];    // per-slot pm column (= old npu)
    __shared__ int s_cpo[SLOTS];    // original current_page
    __shared__ int s_K, s_fe;

    const int4* ps4 = reinterpret_cast<const int4*>(ps);
    const int gi = b * NTHR + t;

    if (wave == 0) {
        // ---- logic wave: logic loads issued BEFORE copy loads --------------
        const int4 sq4 = reinterpret_cast<const int4*>(seq)[lane];
        const int4 cq4 = reinterpret_cast<const int4*>(cp)[lane];
        const int4 nu4 = reinterpret_cast<const int4*>(npu)[lane];
        int4 pc[8];
        #pragma unroll
        for (int r = 0; r < 8; ++r) pc[r] = ps4[r * 64 + lane];  // pages 0..2047
        const int4 pv = ps4[gi];
        const int4 mv = reinterpret_cast<const int4*>(pm)[gi];

        // ---- slot math, 4 slots/lane (slot = 4*lane+j) ----------------------
        int ns0, ns1, ns2, ns3, nn0, nn1, nn2, nn3, nb = 0;
        ns0 = sq4.x + (cq4.x != -1); nn0 = (ns0 + TPP - 1) / TPP; if (nn0 > nu4.x) nb |= 1;
        ns1 = sq4.y + (cq4.y != -1); nn1 = (ns1 + TPP - 1) / TPP; if (nn1 > nu4.y) nb |= 2;
        ns2 = sq4.z + (cq4.z != -1); nn2 = (ns2 + TPP - 1) / TPP; if (nn2 > nu4.z) nb |= 4;
        ns3 = sq4.w + (cq4.w != -1); nn3 = (ns3 + TPP - 1) / TPP; if (nn3 > nu4.w) nb |= 8;

        if (b == 0) {   // slot vectors, vectorized stores (never patched later)
            int4 o;
            o.x = ns0; o.y = ns1; o.z = ns2; o.w = ns3;
            reinterpret_cast<int4*>(out_seq)[lane] = o;
            o.x = nn0; o.y = nn1; o.z = nn2; o.w = nn3;
            reinterpret_cast<int4*>(out_npu)[lane] = o;
            o.x = (ns0 == 0) ? 0 : ((ns0 - 1) & (TPP - 1));
            o.y = (ns1 == 0) ? 0 : ((ns1 - 1) & (TPP - 1));
            o.z = (ns2 == 0) ? 0 : ((ns2 - 1) & (TPP - 1));
            o.w = (ns3 == 0) ? 0 : ((ns3 - 1) & (TPP - 1));
            reinterpret_cast<int4*>(out_cpp)[lane] = o;
        }

        // ---- needs rank via one wave scan -----------------------------------
        int cnt = __popc(nb), x = cnt;
        #pragma unroll
        for (int o = 1; o < 64; o <<= 1) { int y = __shfl_up(x, o); if (lane >= o) x += y; }
        const int K = __shfl(x, 63);
        const int base_r = x - cnt;
        int4 iv;
        iv.x = (nb & 1) ? base_r : -1;
        iv.y = (nb & 2) ? base_r + __popc(nb & 1) : -1;
        iv.z = (nb & 4) ? base_r + __popc(nb & 3) : -1;
        iv.w = (nb & 8) ? base_r + __popc(nb & 7) : -1;
        reinterpret_cast<int4*>(s_info)[lane] = iv;
        reinterpret_cast<int4*>(s_col)[lane]  = nu4;
        reinterpret_cast<int4*>(s_cpo)[lane]  = cq4;

        // ---- free-page scan: shfl-only, s_found in uniform registers --------
        auto doRound = [&](int4 v, int pagebase, int sf) -> int {
            int m = ((v.x == 0) ? 1 : 0) | ((v.y == 0) ? 2 : 0) |
                    ((v.z == 0) ? 4 : 0) | ((v.w == 0) ? 8 : 0);
            if (pagebase == 0 && lane == 0) m &= ~1;   // page 0 not allocatable
            int q = __popc(m), xx = q;
            #pragma unroll
            for (int o = 1; o < 64; o <<= 1) { int y = __shfl_up(xx, o); if (lane >= o) xx += y; }
            int pos = sf + xx - q;
            #pragma unroll
            for (int j = 0; j < 4; ++j) if (m & (1 << j)) {
                int p = pos + __popc(m & ((1 << j) - 1));
                if (p < K) s_free[p] = pagebase + lane * 4 + j;
            }
            return sf + __shfl(xx, 63);
        };

        int sf = 0;
        #pragma unroll
        for (int r = 0; r < 8; ++r)
            if (sf < K) sf = doRound(pc[r], r * 256, sf);
        for (int pb = 2048; pb < NUM_PAGES && sf < K; pb += 256)   // cold fallback
            sf = doRound(ps4[(pb >> 2) + lane], pb, sf);

        if (lane == 0) { s_K = K; s_fe = (sf < K) ? sf : K; }

        // copy stores (data long since arrived; overlapped with logic)
        reinterpret_cast<int4*>(out_ps)[gi] = pv;
        reinterpret_cast<int4*>(out_pm)[gi] = mv;
    } else {
        // ---- pure copy waves ------------------------------------------------
        const int4 pv = ps4[gi];
        const int4 mv = reinterpret_cast<const int4*>(pm)[gi];
        reinterpret_cast<int4*>(out_ps)[gi] = pv;
        reinterpret_cast<int4*>(out_pm)[gi] = mv;
    }

    __syncthreads();    // the ONLY barrier: publish LDS + drain copy stores

    const int K = s_K, fe = s_fe;

    // ps patch: by the block owning that ps chunk (chunk = page >> 10)
    if (t < K) {
        int f = (t < fe) ? s_free[t] : 0;   // exhausted pool -> page 0
        if ((f >> 10) == b) out_ps[f] = 1;
    }
    // pm patch: block b owns pm elements [b*1024, +1024): slot b>>2, col range (b&3)*1024..
    if (t == 64) {
        int slot = b >> 2, info = s_info[slot];
        if (info >= 0) {
            int col = s_col[slot];
            if ((col >> 10) == (b & 3))
                out_pm[slot * MPPS + col] = (info < fe) ? s_free[info] : 0;
        }
    }
    // cp vector: block 0 (one thread per slot)
    if (b == 0) {
        int info = s_info[t];
        out_cp[t] = (info >= 0) ? ((info < fe) ? s_free[info] : 0) : s_cpo[t];
    }
}

// ---------------------------------------------------------------------------
extern "C" void kernel_launch(void* const* d_in, const int* in_sizes, int n_in,
                              void* d_out, int out_size, void* d_ws, size_t ws_size,
                              hipStream_t stream)
{
    const int* page_status = (const int*)d_in[0];
    const int* page_map    = (const int*)d_in[1];
    const int* seq         = (const int*)d_in[2];
    const int* npu         = (const int*)d_in[3];
    const int* cp          = (const int*)d_in[4];
    // d_in[5] (current_page_position) unused by the reference update.

    fused<<<NBLK, NTHR, 0, stream>>>(
        page_status, page_map, seq, npu, cp, (int*)d_out);
}